// Round 7
// baseline (382.854 us; speedup 1.0000x reference)
//
#include <hip/hip_runtime.h>

typedef __attribute__((ext_vector_type(8))) short bf16x8;
typedef __attribute__((ext_vector_type(4))) float f32x4;
typedef __attribute__((ext_vector_type(16))) float f32x16;
typedef unsigned short u16;
typedef unsigned int u32;

namespace {
constexpr int kB = 8;
constexpr int kC = 512;
constexpr int kCK = 64;
constexpr int kN = 4096;

__device__ __forceinline__ u16 f2bf(float f) {
  union { float f; u32 u; } v; v.f = f;
  u32 r = v.u + 0x7fffu + ((v.u >> 16) & 1u);   // RNE
  return (u16)(r >> 16);
}
__device__ __forceinline__ u32 pk2bf(float a, float b) {
  return (u32)f2bf(a) | ((u32)f2bf(b) << 16);
}
__device__ __forceinline__ f32x4 zero4() { f32x4 z = {0.f, 0.f, 0.f, 0.f}; return z; }
}

// Cast Wf(64x512), Wg(64x512), Wh(512x512) fp32 -> bf16 into Wcat[640][512].
__global__ __launch_bounds__(256)
void wcast_kernel(const float* __restrict__ Wf, const float* __restrict__ Wg,
                  const float* __restrict__ Wh, u16* __restrict__ Wcat)
{
  const int idx = blockIdx.x * 256 + threadIdx.x;   // one float4 each
  const int e = idx * 4;                            // 0 .. 327680
  const int row = e >> 9, col = e & 511;
  const float* src = (row < 64) ? &Wf[(size_t)row * 512 + col]
                   : (row < 128) ? &Wg[(size_t)(row - 64) * 512 + col]
                                 : &Wh[(size_t)(row - 128) * 512 + col];
  const float4 v = *(const float4*)src;
  uint2 pk;
  pk.x = pk2bf(v.x, v.y);
  pk.y = pk2bf(v.z, v.w);
  *(uint2*)&Wcat[e] = pk;
}

// Fused projections via MFMA. grid: (N/64, B), block 256 (4 waves).
__global__ __launch_bounds__(256, 2)
void fused_proj_kernel(const float* __restrict__ x, const u16* __restrict__ Wcat,
                       const float* __restrict__ Wf_b, const float* __restrict__ Wg_b,
                       const float* __restrict__ Wh_b,
                       u16* __restrict__ F, u16* __restrict__ G, u16* __restrict__ HT)
{
  const int t = threadIdx.x;
  const int nt = blockIdx.x, b = blockIdx.y;
  const int wave = t >> 6, lane = t & 63, lq = lane & 15, lk = lane >> 4;

  __shared__ __align__(16) u16 xt[64][536];   // [n][c], row stride 1072B

  const float* xb = x + (size_t)b * kC * kN + (size_t)nt * 64;
  for (int c0 = 0; c0 < kC; c0 += 16) {
    const int c = c0 + wave * 4;
    const size_t base = (size_t)c * kN + lane;
    const float v0 = xb[base];
    const float v1 = xb[base + kN];
    const float v2 = xb[base + 2 * (size_t)kN];
    const float v3 = xb[base + 3 * (size_t)kN];
    uint2 pk; pk.x = pk2bf(v0, v1); pk.y = pk2bf(v2, v3);
    *(uint2*)&xt[lane][c] = pk;
  }
  __syncthreads();

  f32x4 accF[4], accG[4], accH[8][4];
#pragma unroll
  for (int ni = 0; ni < 4; ++ni) { accF[ni] = zero4(); accG[ni] = zero4(); }
#pragma unroll
  for (int cj = 0; cj < 8; ++cj)
#pragma unroll
    for (int ni = 0; ni < 4; ++ni) accH[cj][ni] = zero4();

  for (int ks = 0; ks < 16; ++ks) {
    const int kb = ks * 32 + lk * 8;
    bf16x8 xf[4];
#pragma unroll
    for (int ni = 0; ni < 4; ++ni)
      xf[ni] = *(const bf16x8*)&xt[ni * 16 + lq][kb];

    const bf16x8 wf = *(const bf16x8*)&Wcat[(size_t)(wave * 16 + lq) * 512 + kb];
    const bf16x8 wg = *(const bf16x8*)&Wcat[(size_t)(64 + wave * 16 + lq) * 512 + kb];
    bf16x8 wh[8];
#pragma unroll
    for (int cj = 0; cj < 8; ++cj)
      wh[cj] = *(const bf16x8*)&Wcat[(size_t)(128 + wave * 128 + cj * 16 + lq) * 512 + kb];

#pragma unroll
    for (int ni = 0; ni < 4; ++ni) {
      accF[ni] = __builtin_amdgcn_mfma_f32_16x16x32_bf16(wf, xf[ni], accF[ni], 0, 0, 0);
      accG[ni] = __builtin_amdgcn_mfma_f32_16x16x32_bf16(wg, xf[ni], accG[ni], 0, 0, 0);
#pragma unroll
      for (int cj = 0; cj < 8; ++cj)
        accH[cj][ni] = __builtin_amdgcn_mfma_f32_16x16x32_bf16(xf[ni], wh[cj], accH[cj][ni], 0, 0, 0);
    }
  }

  u16* Fb = F + (size_t)b * kN * kCK;
  u16* Gb = G + (size_t)b * kN * kCK;
  u16* Hb = HT + (size_t)b * kC * kN;

  {
    const float4 bf = *(const float4*)&Wf_b[wave * 16 + lk * 4];
    const float4 bg = *(const float4*)&Wg_b[wave * 16 + lk * 4];
#pragma unroll
    for (int ni = 0; ni < 4; ++ni) {
      const size_t nrow = (size_t)(nt * 64 + ni * 16 + lq);
      uint2 pf, pg;
      pf.x = pk2bf(accF[ni][0] + bf.x, accF[ni][1] + bf.y);
      pf.y = pk2bf(accF[ni][2] + bf.z, accF[ni][3] + bf.w);
      pg.x = pk2bf(accG[ni][0] + bg.x, accG[ni][1] + bg.y);
      pg.y = pk2bf(accG[ni][2] + bg.z, accG[ni][3] + bg.w);
      *(uint2*)&Fb[nrow * kCK + wave * 16 + lk * 4] = pf;
      *(uint2*)&Gb[nrow * kCK + wave * 16 + lk * 4] = pg;
    }
  }
#pragma unroll
  for (int cj = 0; cj < 8; ++cj) {
    const int cout = wave * 128 + cj * 16 + lq;
    const float bh = Wh_b[cout];
#pragma unroll
    for (int ni = 0; ni < 4; ++ni) {
      uint2 ph;
      ph.x = pk2bf(accH[cj][ni][0] + bh, accH[cj][ni][1] + bh);
      ph.y = pk2bf(accH[cj][ni][2] + bh, accH[cj][ni][3] + bh);
      *(uint2*)&Hb[(size_t)cout * kN + nt * 64 + ni * 16 + lk * 4] = ph;
    }
  }
}

// Row max and 1/sum(exp) of scores. grid 512 (b = bid&7), block 256.
__global__ __launch_bounds__(256)
void stats_kernel(const u16* __restrict__ F, const u16* __restrict__ G,
                  float* __restrict__ rowmax, float* __restrict__ rsinv)
{
  const int t = threadIdx.x;
  const int bid = blockIdx.x;
  const int b = bid & 7, qt = bid >> 3;
  const int wave = t >> 6, lane = t & 63, lq = lane & 15, lk = lane >> 4;

  const u16* Fb = F + (size_t)b * kN * kCK;
  const u16* Gb = G + (size_t)b * kN * kCK;

  bf16x8 fF[4][2];
#pragma unroll
  for (int ct = 0; ct < 4; ++ct)
#pragma unroll
    for (int ks = 0; ks < 2; ++ks)
      fF[ct][ks] = *(const bf16x8*)&Fb[(size_t)(qt * 64 + ct * 16 + lq) * kCK + lk * 8 + ks * 32];

  float mold[4], lsum[4];
#pragma unroll
  for (int ct = 0; ct < 4; ++ct) { mold[ct] = -3.0e38f; lsum[ct] = 0.f; }

  bf16x8 g0c = *(const bf16x8*)&Gb[(size_t)(wave * 16 + lq) * kCK + lk * 8];
  bf16x8 g1c = *(const bf16x8*)&Gb[(size_t)(wave * 16 + lq) * kCK + lk * 8 + 32];

  for (int mt = 0; mt < kN / 64; ++mt) {
    const int mtn = (mt + 1 < kN / 64) ? mt + 1 : mt;
    const size_t gbase = (size_t)(mtn * 64 + wave * 16 + lq) * kCK + lk * 8;
    bf16x8 g0n = *(const bf16x8*)&Gb[gbase];
    bf16x8 g1n = *(const bf16x8*)&Gb[gbase + 32];

    f32x4 s[4];
#pragma unroll
    for (int ct = 0; ct < 4; ++ct) {
      s[ct] = zero4();
      s[ct] = __builtin_amdgcn_mfma_f32_16x16x32_bf16(g0c, fF[ct][0], s[ct], 0, 0, 0);
      s[ct] = __builtin_amdgcn_mfma_f32_16x16x32_bf16(g1c, fF[ct][1], s[ct], 0, 0, 0);
    }
#pragma unroll
    for (int ct = 0; ct < 4; ++ct) {
      float tm = fmaxf(fmaxf(s[ct][0], s[ct][1]), fmaxf(s[ct][2], s[ct][3]));
      tm = fmaxf(tm, __shfl_xor(tm, 16));
      tm = fmaxf(tm, __shfl_xor(tm, 32));
      const float mnew = fmaxf(mold[ct], tm);
      float ls = __expf(s[ct][0] - mnew) + __expf(s[ct][1] - mnew) +
                 __expf(s[ct][2] - mnew) + __expf(s[ct][3] - mnew);
      ls += __shfl_xor(ls, 16);
      ls += __shfl_xor(ls, 32);
      lsum[ct] = lsum[ct] * __expf(mold[ct] - mnew) + ls;
      mold[ct] = mnew;
    }
    g0c = g0n; g1c = g1n;
  }

  __shared__ float red[2][4][64];
  if (lane < 16) {
#pragma unroll
    for (int ct = 0; ct < 4; ++ct) {
      red[0][wave][ct * 16 + lane] = mold[ct];
      red[1][wave][ct * 16 + lane] = lsum[ct];
    }
  }
  __syncthreads();
  if (t < 64) {
    float M = fmaxf(fmaxf(red[0][0][t], red[0][1][t]), fmaxf(red[0][2][t], red[0][3][t]));
    float L = 0.f;
#pragma unroll
    for (int w = 0; w < 4; ++w) L += red[1][w][t] * __expf(red[0][w][t] - M);
    rowmax[(size_t)b * kN + qt * 64 + t] = M;
    rsinv[(size_t)b * kN + qt * 64 + t] = 1.f / L;
  }
}

// pv v4b: two independent 256-thread blocks per CU (barrier decoupling),
// softmax math identical to the verified R5 kernel (p = exp(s-rmax)*rsv,
// manual RNE bf16 pack).
// grid 512: b=bid&7 (XCD pin), qt=(bid>>3)&31 (q-tile 128), cs=bid>>8.
// Per block (4 waves): q=128, c=256, m-step 64.
//  S role:  wave owns q-strip 32 (ct 2x16), all 64 m (ms 4x16): 16 MFMA 16x16x32.
//  PV role: wave owns c-strip 64 (ci 2x32), all 128 q (qb 4x32): 32 MFMA 32x32x16.
__global__ __launch_bounds__(256, 2)
void pv_kernel(const float* __restrict__ x, const u16* __restrict__ F,
               const u16* __restrict__ G, const u16* __restrict__ HT,
               const float* __restrict__ rowmax, const float* __restrict__ rsinv,
               const float* __restrict__ gamma, float* __restrict__ out)
{
  const int t = threadIdx.x;
  const int bid = blockIdx.x;
  const int b  = bid & 7;
  const int r2 = bid >> 3;          // 0..63
  const int qt = r2 & 31;           // q-tile of 128
  const int cs = r2 >> 5;           // 0..1 (c-half of 256)
  const int wave = t >> 6, lane = t & 63;
  const int lq = lane & 15, lk = lane >> 4;
  const int l31 = lane & 31, hi = lane >> 5;

  const u16* Fb = F + (size_t)b * kN * kCK;
  const u16* Gb = G + (size_t)b * kN * kCK;
  const u16* Hb = HT + (size_t)b * kC * kN;

  __shared__ __align__(16) u16 Ps[2][128][72];   // [buf][q][m], 36 KB

  // softmax constants for this wave's S q-strip (R5-proven form)
  float rmax[2], rsv[2];
#pragma unroll
  for (int ct = 0; ct < 2; ++ct) {
    const size_t q = (size_t)b * kN + qt * 128 + wave * 32 + ct * 16 + lq;
    rmax[ct] = rowmax[q];
    rsv[ct] = rsinv[q];
  }
  const float g0 = gamma[0];

  // F B-frags (held whole kernel): q-strip of this wave
  bf16x8 fF[2][2];
#pragma unroll
  for (int ct = 0; ct < 2; ++ct)
#pragma unroll
    for (int kh = 0; kh < 2; ++kh)
      fF[ct][kh] = *(const bf16x8*)&Fb[(size_t)(qt * 128 + wave * 32 + ct * 16 + lq) * kCK + lk * 8 + kh * 32];

  f32x16 acc[2][4];
#pragma unroll
  for (int ci = 0; ci < 2; ++ci)
#pragma unroll
    for (int qb = 0; qb < 4; ++qb)
#pragma unroll
      for (int r = 0; r < 16; ++r) acc[ci][qb][r] = 0.f;

  // G A-frags for mt=0 (all 64 m, 4 subtiles)
  bf16x8 gc[4][2];
#pragma unroll
  for (int ms = 0; ms < 4; ++ms)
#pragma unroll
    for (int kh = 0; kh < 2; ++kh)
      gc[ms][kh] = *(const bf16x8*)&Gb[(size_t)(ms * 16 + lq) * kCK + lk * 8 + kh * 32];

  // H frags (PV A-operands): loaded each iter pre-barrier, consumed next top.
  bf16x8 hc[2][4];
#pragma unroll
  for (int ci = 0; ci < 2; ++ci)
#pragma unroll
    for (int ks = 0; ks < 4; ++ks) hc[ci][ks] = bf16x8{0,0,0,0,0,0,0,0};

  for (int mt = 0; mt < kN / 64; ++mt) {
    // ---- PV of tile mt-1
    if (mt > 0) {
      const int pb = (mt - 1) & 1;
#pragma unroll
      for (int ks = 0; ks < 4; ++ks) {
        bf16x8 pB[4];
#pragma unroll
        for (int qb = 0; qb < 4; ++qb)
          pB[qb] = *(const bf16x8*)&Ps[pb][qb * 32 + l31][ks * 16 + hi * 8];
#pragma unroll
        for (int ci = 0; ci < 2; ++ci)
#pragma unroll
          for (int qb = 0; qb < 4; ++qb)
            acc[ci][qb] = __builtin_amdgcn_mfma_f32_32x32x16_bf16(hc[ci][ks], pB[qb], acc[ci][qb], 0, 0, 0);
      }
    }

    // ---- S^T for this wave: [64 m][32 q]
    f32x4 s[4][2];
#pragma unroll
    for (int ms = 0; ms < 4; ++ms)
#pragma unroll
      for (int ct = 0; ct < 2; ++ct) {
        s[ms][ct] = zero4();
        s[ms][ct] = __builtin_amdgcn_mfma_f32_16x16x32_bf16(gc[ms][0], fF[ct][0], s[ms][ct], 0, 0, 0);
        s[ms][ct] = __builtin_amdgcn_mfma_f32_16x16x32_bf16(gc[ms][1], fF[ct][1], s[ms][ct], 0, 0, 0);
      }

    // ---- G prefetch for mt+1
    {
      const int mtn = (mt + 1 < kN / 64) ? mt + 1 : mt;
#pragma unroll
      for (int ms = 0; ms < 4; ++ms)
#pragma unroll
        for (int kh = 0; kh < 2; ++kh)
          gc[ms][kh] = *(const bf16x8*)&Gb[(size_t)(mtn * 64 + ms * 16 + lq) * kCK + lk * 8 + kh * 32];
    }

    // ---- normalized P -> bf16 -> Ps[mt&1] (R5-proven math)
    const int buf = mt & 1;
#pragma unroll
    for (int ms = 0; ms < 4; ++ms)
#pragma unroll
      for (int ct = 0; ct < 2; ++ct) {
        const float p0 = __expf(s[ms][ct][0] - rmax[ct]) * rsv[ct];
        const float p1 = __expf(s[ms][ct][1] - rmax[ct]) * rsv[ct];
        const float p2 = __expf(s[ms][ct][2] - rmax[ct]) * rsv[ct];
        const float p3 = __expf(s[ms][ct][3] - rmax[ct]) * rsv[ct];
        uint2 pk; pk.x = pk2bf(p0, p1); pk.y = pk2bf(p2, p3);
        *(uint2*)&Ps[buf][wave * 32 + ct * 16 + lq][ms * 16 + lk * 4] = pk;
      }

    // ---- H frags for THIS mt (consumed next top / drain); in flight across barrier
#pragma unroll
    for (int ci = 0; ci < 2; ++ci) {
      const size_t hrow = (size_t)(cs * 256 + wave * 64 + ci * 32 + l31) * kN + (size_t)mt * 64;
#pragma unroll
      for (int ks = 0; ks < 4; ++ks)
        hc[ci][ks] = *(const bf16x8*)&Hb[hrow + ks * 16 + hi * 8];
    }

    // single barrier per iter; LDS drained, global loads stay in flight
    asm volatile("s_waitcnt lgkmcnt(0)\n\ts_barrier" ::: "memory");
  }

  // ---- drain: PV of the last tile
  {
    const int pb = (kN / 64 - 1) & 1;
#pragma unroll
    for (int ks = 0; ks < 4; ++ks) {
      bf16x8 pB[4];
#pragma unroll
      for (int qb = 0; qb < 4; ++qb)
        pB[qb] = *(const bf16x8*)&Ps[pb][qb * 32 + l31][ks * 16 + hi * 8];
#pragma unroll
      for (int ci = 0; ci < 2; ++ci)
#pragma unroll
        for (int qb = 0; qb < 4; ++qb)
          acc[ci][qb] = __builtin_amdgcn_mfma_f32_32x32x16_bf16(hc[ci][ks], pB[qb], acc[ci][qb], 0, 0, 0);
    }
  }

  // ---- epilogue: D col=l31=q, row=(r&3)+8*(r>>2)+4*hi = c-within-32
#pragma unroll
  for (int ci = 0; ci < 2; ++ci)
#pragma unroll
    for (int qb = 0; qb < 4; ++qb)
#pragma unroll
      for (int r = 0; r < 16; ++r) {
        const int crow = (r & 3) + 8 * (r >> 2) + 4 * hi;
        const int c = cs * 256 + wave * 64 + ci * 32 + crow;
        const int n = qt * 128 + qb * 32 + l31;
        const size_t idx = ((size_t)b * kC + c) * kN + n;
        out[idx] = g0 * acc[ci][qb][r] + x[idx];
      }
}

extern "C" void kernel_launch(void* const* d_in, const int* in_sizes, int n_in,
                              void* d_out, int out_size, void* d_ws, size_t ws_size,
                              hipStream_t stream)
{
  const float* x     = (const float*)d_in[0];
  const float* Wf_w  = (const float*)d_in[1];
  const float* Wf_b  = (const float*)d_in[2];
  const float* Wg_w  = (const float*)d_in[3];
  const float* Wg_b  = (const float*)d_in[4];
  const float* Wh_w  = (const float*)d_in[5];
  const float* Wh_b  = (const float*)d_in[6];
  const float* gamma = (const float*)d_in[7];
  float* out = (float*)d_out;

  const size_t nF = (size_t)kB * kN * kCK;   // 2,097,152
  const size_t nH = (size_t)kB * kC * kN;    // 16,777,216
  const size_t nR = (size_t)kB * kN;         // 32,768
  const size_t nW = 640 * 512;               // 327,680

  u16* F  = (u16*)d_ws;
  u16* G  = F + nF;
  u16* HT = G + nF;
  u16* Wcat = HT + nH;
  float* rowmax = (float*)(Wcat + nW);
  float* rsinv  = rowmax + nR;
  const size_t need = (2 * nF + nH + nW) * sizeof(u16) + 2 * nR * sizeof(float);
  if (ws_size < need) return;

  wcast_kernel<<<dim3(nW / 1024), dim3(256), 0, stream>>>(Wf_w, Wg_w, Wh_w, Wcat);
  fused_proj_kernel<<<dim3(kN / 64, kB), dim3(256), 0, stream>>>(x, Wcat, Wf_b, Wg_b, Wh_b, F, G, HT);
  stats_kernel<<<dim3(512), dim3(256), 0, stream>>>(F, G, rowmax, rsinv);
  pv_kernel<<<dim3(512), dim3(256), 0, stream>>>(x, F, G, HT, rowmax, rsinv, gamma, out);
}

// Round 8
// 327.080 us; speedup vs baseline: 1.1705x; 1.1705x over previous
//
#include <hip/hip_runtime.h>

typedef __attribute__((ext_vector_type(8))) short bf16x8;
typedef __attribute__((ext_vector_type(4))) float f32x4;
typedef __attribute__((ext_vector_type(16))) float f32x16;
typedef unsigned short u16;
typedef unsigned int u32;

namespace {
constexpr int kB = 8;
constexpr int kC = 512;
constexpr int kCK = 64;
constexpr int kN = 4096;

__device__ __forceinline__ u16 f2bf(float f) {
  union { float f; u32 u; } v; v.f = f;
  u32 r = v.u + 0x7fffu + ((v.u >> 16) & 1u);   // RNE
  return (u16)(r >> 16);
}
__device__ __forceinline__ u32 pk2bf(float a, float b) {
  return (u32)f2bf(a) | ((u32)f2bf(b) << 16);
}
__device__ __forceinline__ f32x4 zero4() { f32x4 z = {0.f, 0.f, 0.f, 0.f}; return z; }
}

// Cast Wf(64x512), Wg(64x512), Wh(512x512) fp32 -> bf16 into Wcat[640][512].
__global__ __launch_bounds__(256)
void wcast_kernel(const float* __restrict__ Wf, const float* __restrict__ Wg,
                  const float* __restrict__ Wh, u16* __restrict__ Wcat)
{
  const int idx = blockIdx.x * 256 + threadIdx.x;   // one float4 each
  const int e = idx * 4;                            // 0 .. 327680
  const int row = e >> 9, col = e & 511;
  const float* src = (row < 64) ? &Wf[(size_t)row * 512 + col]
                   : (row < 128) ? &Wg[(size_t)(row - 64) * 512 + col]
                                 : &Wh[(size_t)(row - 128) * 512 + col];
  const float4 v = *(const float4*)src;
  uint2 pk;
  pk.x = pk2bf(v.x, v.y);
  pk.y = pk2bf(v.z, v.w);
  *(uint2*)&Wcat[e] = pk;
}

// Fused projections via MFMA. grid: (N/64, B), block 256 (4 waves).
__global__ __launch_bounds__(256, 2)
void fused_proj_kernel(const float* __restrict__ x, const u16* __restrict__ Wcat,
                       const float* __restrict__ Wf_b, const float* __restrict__ Wg_b,
                       const float* __restrict__ Wh_b,
                       u16* __restrict__ F, u16* __restrict__ G, u16* __restrict__ HT)
{
  const int t = threadIdx.x;
  const int nt = blockIdx.x, b = blockIdx.y;
  const int wave = t >> 6, lane = t & 63, lq = lane & 15, lk = lane >> 4;

  __shared__ __align__(16) u16 xt[64][536];   // [n][c], row stride 1072B

  const float* xb = x + (size_t)b * kC * kN + (size_t)nt * 64;
  for (int c0 = 0; c0 < kC; c0 += 16) {
    const int c = c0 + wave * 4;
    const size_t base = (size_t)c * kN + lane;
    const float v0 = xb[base];
    const float v1 = xb[base + kN];
    const float v2 = xb[base + 2 * (size_t)kN];
    const float v3 = xb[base + 3 * (size_t)kN];
    uint2 pk; pk.x = pk2bf(v0, v1); pk.y = pk2bf(v2, v3);
    *(uint2*)&xt[lane][c] = pk;
  }
  __syncthreads();

  f32x4 accF[4], accG[4], accH[8][4];
#pragma unroll
  for (int ni = 0; ni < 4; ++ni) { accF[ni] = zero4(); accG[ni] = zero4(); }
#pragma unroll
  for (int cj = 0; cj < 8; ++cj)
#pragma unroll
    for (int ni = 0; ni < 4; ++ni) accH[cj][ni] = zero4();

  for (int ks = 0; ks < 16; ++ks) {
    const int kb = ks * 32 + lk * 8;
    bf16x8 xf[4];
#pragma unroll
    for (int ni = 0; ni < 4; ++ni)
      xf[ni] = *(const bf16x8*)&xt[ni * 16 + lq][kb];

    const bf16x8 wf = *(const bf16x8*)&Wcat[(size_t)(wave * 16 + lq) * 512 + kb];
    const bf16x8 wg = *(const bf16x8*)&Wcat[(size_t)(64 + wave * 16 + lq) * 512 + kb];
    bf16x8 wh[8];
#pragma unroll
    for (int cj = 0; cj < 8; ++cj)
      wh[cj] = *(const bf16x8*)&Wcat[(size_t)(128 + wave * 128 + cj * 16 + lq) * 512 + kb];

#pragma unroll
    for (int ni = 0; ni < 4; ++ni) {
      accF[ni] = __builtin_amdgcn_mfma_f32_16x16x32_bf16(wf, xf[ni], accF[ni], 0, 0, 0);
      accG[ni] = __builtin_amdgcn_mfma_f32_16x16x32_bf16(wg, xf[ni], accG[ni], 0, 0, 0);
#pragma unroll
      for (int cj = 0; cj < 8; ++cj)
        accH[cj][ni] = __builtin_amdgcn_mfma_f32_16x16x32_bf16(xf[ni], wh[cj], accH[cj][ni], 0, 0, 0);
    }
  }

  u16* Fb = F + (size_t)b * kN * kCK;
  u16* Gb = G + (size_t)b * kN * kCK;
  u16* Hb = HT + (size_t)b * kC * kN;

  {
    const float4 bf = *(const float4*)&Wf_b[wave * 16 + lk * 4];
    const float4 bg = *(const float4*)&Wg_b[wave * 16 + lk * 4];
#pragma unroll
    for (int ni = 0; ni < 4; ++ni) {
      const size_t nrow = (size_t)(nt * 64 + ni * 16 + lq);
      uint2 pf, pg;
      pf.x = pk2bf(accF[ni][0] + bf.x, accF[ni][1] + bf.y);
      pf.y = pk2bf(accF[ni][2] + bf.z, accF[ni][3] + bf.w);
      pg.x = pk2bf(accG[ni][0] + bg.x, accG[ni][1] + bg.y);
      pg.y = pk2bf(accG[ni][2] + bg.z, accG[ni][3] + bg.w);
      *(uint2*)&Fb[nrow * kCK + wave * 16 + lk * 4] = pf;
      *(uint2*)&Gb[nrow * kCK + wave * 16 + lk * 4] = pg;
    }
  }
#pragma unroll
  for (int cj = 0; cj < 8; ++cj) {
    const int cout = wave * 128 + cj * 16 + lq;
    const float bh = Wh_b[cout];
#pragma unroll
    for (int ni = 0; ni < 4; ++ni) {
      uint2 ph;
      ph.x = pk2bf(accH[cj][ni][0] + bh, accH[cj][ni][1] + bh);
      ph.y = pk2bf(accH[cj][ni][2] + bh, accH[cj][ni][3] + bh);
      *(uint2*)&Hb[(size_t)cout * kN + nt * 64 + ni * 16 + lk * 4] = ph;
    }
  }
}

// Row max and 1/sum(exp) of scores. grid 512 (b = bid&7), block 256.
__global__ __launch_bounds__(256)
void stats_kernel(const u16* __restrict__ F, const u16* __restrict__ G,
                  float* __restrict__ rowmax, float* __restrict__ rsinv)
{
  const int t = threadIdx.x;
  const int bid = blockIdx.x;
  const int b = bid & 7, qt = bid >> 3;
  const int wave = t >> 6, lane = t & 63, lq = lane & 15, lk = lane >> 4;

  const u16* Fb = F + (size_t)b * kN * kCK;
  const u16* Gb = G + (size_t)b * kN * kCK;

  bf16x8 fF[4][2];
#pragma unroll
  for (int ct = 0; ct < 4; ++ct)
#pragma unroll
    for (int ks = 0; ks < 2; ++ks)
      fF[ct][ks] = *(const bf16x8*)&Fb[(size_t)(qt * 64 + ct * 16 + lq) * kCK + lk * 8 + ks * 32];

  float mold[4], lsum[4];
#pragma unroll
  for (int ct = 0; ct < 4; ++ct) { mold[ct] = -3.0e38f; lsum[ct] = 0.f; }

  bf16x8 g0c = *(const bf16x8*)&Gb[(size_t)(wave * 16 + lq) * kCK + lk * 8];
  bf16x8 g1c = *(const bf16x8*)&Gb[(size_t)(wave * 16 + lq) * kCK + lk * 8 + 32];

  for (int mt = 0; mt < kN / 64; ++mt) {
    const int mtn = (mt + 1 < kN / 64) ? mt + 1 : mt;
    const size_t gbase = (size_t)(mtn * 64 + wave * 16 + lq) * kCK + lk * 8;
    bf16x8 g0n = *(const bf16x8*)&Gb[gbase];
    bf16x8 g1n = *(const bf16x8*)&Gb[gbase + 32];

    f32x4 s[4];
#pragma unroll
    for (int ct = 0; ct < 4; ++ct) {
      s[ct] = zero4();
      s[ct] = __builtin_amdgcn_mfma_f32_16x16x32_bf16(g0c, fF[ct][0], s[ct], 0, 0, 0);
      s[ct] = __builtin_amdgcn_mfma_f32_16x16x32_bf16(g1c, fF[ct][1], s[ct], 0, 0, 0);
    }
#pragma unroll
    for (int ct = 0; ct < 4; ++ct) {
      float tm = fmaxf(fmaxf(s[ct][0], s[ct][1]), fmaxf(s[ct][2], s[ct][3]));
      tm = fmaxf(tm, __shfl_xor(tm, 16));
      tm = fmaxf(tm, __shfl_xor(tm, 32));
      const float mnew = fmaxf(mold[ct], tm);
      float ls = __expf(s[ct][0] - mnew) + __expf(s[ct][1] - mnew) +
                 __expf(s[ct][2] - mnew) + __expf(s[ct][3] - mnew);
      ls += __shfl_xor(ls, 16);
      ls += __shfl_xor(ls, 32);
      lsum[ct] = lsum[ct] * __expf(mold[ct] - mnew) + ls;
      mold[ct] = mnew;
    }
    g0c = g0n; g1c = g1n;
  }

  __shared__ float red[2][4][64];
  if (lane < 16) {
#pragma unroll
    for (int ct = 0; ct < 4; ++ct) {
      red[0][wave][ct * 16 + lane] = mold[ct];
      red[1][wave][ct * 16 + lane] = lsum[ct];
    }
  }
  __syncthreads();
  if (t < 64) {
    float M = fmaxf(fmaxf(red[0][0][t], red[0][1][t]), fmaxf(red[0][2][t], red[0][3][t]));
    float L = 0.f;
#pragma unroll
    for (int w = 0; w < 4; ++w) L += red[1][w][t] * __expf(red[0][w][t] - M);
    rowmax[(size_t)b * kN + qt * 64 + t] = M;
    rsinv[(size_t)b * kN + qt * 64 + t] = 1.f / L;
  }
}

// pv v5: one 512-thread block per CU; q=128, c=512 (no cs split -> S computed
// once, exp work halved). Per iteration: S(mt) FIRST, then PV(mt-1) MFMAs
// interleaved ks-chunk-wise with the exp/pack/ds_write of tile mt (MFMA pipe
// and VALU pipe overlap within the wave). One no-vmcnt barrier per iter.
// grid 256: b=bid&7 (XCD pin), qt=bid>>3 (q-tile of 128).
//  S role:  sq2=wave&3 (q-strip 32), sm2=wave>>2 (m-half 32): 8 MFMA 16x16x32.
//  PV role: wave owns c-strip 64 (ci 2x32), all 128 q (qb 4x32): 32 MFMA 32x32x16.
__global__ __launch_bounds__(512, 2)
void pv_kernel(const float* __restrict__ x, const u16* __restrict__ F,
               const u16* __restrict__ G, const u16* __restrict__ HT,
               const float* __restrict__ rowmax, const float* __restrict__ rsinv,
               const float* __restrict__ gamma, float* __restrict__ out)
{
  const int t = threadIdx.x;
  const int bid = blockIdx.x;
  const int b  = bid & 7;
  const int qt = bid >> 3;          // 0..31, q-tile of 128
  const int wave = t >> 6, lane = t & 63;
  const int lq = lane & 15, lk = lane >> 4;
  const int l31 = lane & 31, hi = lane >> 5;

  const int sq2 = wave & 3;         // S: q-strip (32) within 128
  const int sm2 = wave >> 2;        // S: m-half (32) within 64

  const u16* Fb = F + (size_t)b * kN * kCK;
  const u16* Gb = G + (size_t)b * kN * kCK;
  const u16* Hb = HT + (size_t)b * kC * kN;

  __shared__ __align__(16) u16 Ps[2][128][72];   // [buf][q][m], 36 KB

  // softmax constants (R5-proven form): p = exp(s - rmax) * rsv
  float rmax[2], rsv[2];
#pragma unroll
  for (int ct = 0; ct < 2; ++ct) {
    const size_t q = (size_t)b * kN + qt * 128 + sq2 * 32 + ct * 16 + lq;
    rmax[ct] = rowmax[q];
    rsv[ct] = rsinv[q];
  }
  const float g0 = gamma[0];

  // F B-frags (held whole kernel)
  bf16x8 fF[2][2];
#pragma unroll
  for (int ct = 0; ct < 2; ++ct)
#pragma unroll
    for (int kh = 0; kh < 2; ++kh)
      fF[ct][kh] = *(const bf16x8*)&Fb[(size_t)(qt * 128 + sq2 * 32 + ct * 16 + lq) * kCK + lk * 8 + kh * 32];

  f32x16 acc[2][4];
#pragma unroll
  for (int ci = 0; ci < 2; ++ci)
#pragma unroll
    for (int qb = 0; qb < 4; ++qb)
#pragma unroll
      for (int r = 0; r < 16; ++r) acc[ci][qb][r] = 0.f;

  // G A-frags for mt=0 (this wave's m-half: 2 subtiles)
  bf16x8 gc[2][2];
#pragma unroll
  for (int ms = 0; ms < 2; ++ms)
#pragma unroll
    for (int kh = 0; kh < 2; ++kh)
      gc[ms][kh] = *(const bf16x8*)&Gb[(size_t)(sm2 * 32 + ms * 16 + lq) * kCK + lk * 8 + kh * 32];

  bf16x8 hc[2][4];

  // ================= prologue: tile 0 (S + exp only) =================
  {
    f32x4 s[2][2];
#pragma unroll
    for (int ms = 0; ms < 2; ++ms)
#pragma unroll
      for (int ct = 0; ct < 2; ++ct) {
        s[ms][ct] = zero4();
        s[ms][ct] = __builtin_amdgcn_mfma_f32_16x16x32_bf16(gc[ms][0], fF[ct][0], s[ms][ct], 0, 0, 0);
        s[ms][ct] = __builtin_amdgcn_mfma_f32_16x16x32_bf16(gc[ms][1], fF[ct][1], s[ms][ct], 0, 0, 0);
      }
    // G prefetch for mt=1
#pragma unroll
    for (int ms = 0; ms < 2; ++ms)
#pragma unroll
      for (int kh = 0; kh < 2; ++kh)
        gc[ms][kh] = *(const bf16x8*)&Gb[(size_t)(64 + sm2 * 32 + ms * 16 + lq) * kCK + lk * 8 + kh * 32];
#pragma unroll
    for (int ms = 0; ms < 2; ++ms)
#pragma unroll
      for (int ct = 0; ct < 2; ++ct) {
        const float p0 = __expf(s[ms][ct][0] - rmax[ct]) * rsv[ct];
        const float p1 = __expf(s[ms][ct][1] - rmax[ct]) * rsv[ct];
        const float p2 = __expf(s[ms][ct][2] - rmax[ct]) * rsv[ct];
        const float p3 = __expf(s[ms][ct][3] - rmax[ct]) * rsv[ct];
        uint2 pk; pk.x = pk2bf(p0, p1); pk.y = pk2bf(p2, p3);
        *(uint2*)&Ps[0][sq2 * 32 + ct * 16 + lq][sm2 * 32 + ms * 16 + lk * 4] = pk;
      }
    // H frags for tile 0
#pragma unroll
    for (int ci = 0; ci < 2; ++ci) {
      const size_t hrow = (size_t)(wave * 64 + ci * 32 + l31) * kN;
#pragma unroll
      for (int ks = 0; ks < 4; ++ks)
        hc[ci][ks] = *(const bf16x8*)&Hb[hrow + ks * 16 + hi * 8];
    }
    asm volatile("s_waitcnt lgkmcnt(0)\n\ts_barrier" ::: "memory");
  }

  // ================= main loop: mt = 1..63 =================
  for (int mt = 1; mt < kN / 64; ++mt) {
    const int pb = (mt - 1) & 1;
    const int buf = mt & 1;

    // ---- S(mt): 8 MFMA (results consumed by exp chunks below)
    f32x4 s[2][2];
#pragma unroll
    for (int ms = 0; ms < 2; ++ms)
#pragma unroll
      for (int ct = 0; ct < 2; ++ct) {
        s[ms][ct] = zero4();
        s[ms][ct] = __builtin_amdgcn_mfma_f32_16x16x32_bf16(gc[ms][0], fF[ct][0], s[ms][ct], 0, 0, 0);
        s[ms][ct] = __builtin_amdgcn_mfma_f32_16x16x32_bf16(gc[ms][1], fF[ct][1], s[ms][ct], 0, 0, 0);
      }

    // ---- G prefetch for mt+1
    {
      const int mtn = (mt + 1 < kN / 64) ? mt + 1 : mt;
#pragma unroll
      for (int ms = 0; ms < 2; ++ms)
#pragma unroll
        for (int kh = 0; kh < 2; ++kh)
          gc[ms][kh] = *(const bf16x8*)&Gb[(size_t)(mtn * 64 + sm2 * 32 + ms * 16 + lq) * kCK + lk * 8 + kh * 32];
    }

    // ---- interleave: PV(mt-1) MFMA chunks with exp/pack/write(mt) VALU chunks
#pragma unroll
    for (int ks = 0; ks < 4; ++ks) {
      bf16x8 pB[4];
#pragma unroll
      for (int qb = 0; qb < 4; ++qb)
        pB[qb] = *(const bf16x8*)&Ps[pb][qb * 32 + l31][ks * 16 + hi * 8];
#pragma unroll
      for (int ci = 0; ci < 2; ++ci)
#pragma unroll
        for (int qb = 0; qb < 4; ++qb)
          acc[ci][qb] = __builtin_amdgcn_mfma_f32_32x32x16_bf16(hc[ci][ks], pB[qb], acc[ci][qb], 0, 0, 0);
      // exp chunk ks -> (ms, ct)
      {
        const int ms = ks >> 1, ct = ks & 1;
        const float p0 = __expf(s[ms][ct][0] - rmax[ct]) * rsv[ct];
        const float p1 = __expf(s[ms][ct][1] - rmax[ct]) * rsv[ct];
        const float p2 = __expf(s[ms][ct][2] - rmax[ct]) * rsv[ct];
        const float p3 = __expf(s[ms][ct][3] - rmax[ct]) * rsv[ct];
        uint2 pk; pk.x = pk2bf(p0, p1); pk.y = pk2bf(p2, p3);
        *(uint2*)&Ps[buf][sq2 * 32 + ct * 16 + lq][sm2 * 32 + ms * 16 + lk * 4] = pk;
      }
    }

    // ---- H frags for THIS mt (consumed next iteration / drain)
#pragma unroll
    for (int ci = 0; ci < 2; ++ci) {
      const size_t hrow = (size_t)(wave * 64 + ci * 32 + l31) * kN + (size_t)mt * 64;
#pragma unroll
      for (int ks = 0; ks < 4; ++ks)
        hc[ci][ks] = *(const bf16x8*)&Hb[hrow + ks * 16 + hi * 8];
    }

    // single barrier per iter; LDS drained, global loads stay in flight
    asm volatile("s_waitcnt lgkmcnt(0)\n\ts_barrier" ::: "memory");
  }

  // ================= drain: PV of tile 63 =================
  {
    const int pb = (kN / 64 - 1) & 1;
#pragma unroll
    for (int ks = 0; ks < 4; ++ks) {
      bf16x8 pB[4];
#pragma unroll
      for (int qb = 0; qb < 4; ++qb)
        pB[qb] = *(const bf16x8*)&Ps[pb][qb * 32 + l31][ks * 16 + hi * 8];
#pragma unroll
      for (int ci = 0; ci < 2; ++ci)
#pragma unroll
        for (int qb = 0; qb < 4; ++qb)
          acc[ci][qb] = __builtin_amdgcn_mfma_f32_32x32x16_bf16(hc[ci][ks], pB[qb], acc[ci][qb], 0, 0, 0);
    }
  }

  // ---- epilogue: D col=l31=q, row=(r&3)+8*(r>>2)+4*hi = c-within-32
#pragma unroll
  for (int ci = 0; ci < 2; ++ci)
#pragma unroll
    for (int qb = 0; qb < 4; ++qb)
#pragma unroll
      for (int r = 0; r < 16; ++r) {
        const int crow = (r & 3) + 8 * (r >> 2) + 4 * hi;
        const int c = wave * 64 + ci * 32 + crow;
        const int n = qt * 128 + qb * 32 + l31;
        const size_t idx = ((size_t)b * kC + c) * kN + n;
        out[idx] = g0 * acc[ci][qb][r] + x[idx];
      }
}

extern "C" void kernel_launch(void* const* d_in, const int* in_sizes, int n_in,
                              void* d_out, int out_size, void* d_ws, size_t ws_size,
                              hipStream_t stream)
{
  const float* x     = (const float*)d_in[0];
  const float* Wf_w  = (const float*)d_in[1];
  const float* Wf_b  = (const float*)d_in[2];
  const float* Wg_w  = (const float*)d_in[3];
  const float* Wg_b  = (const float*)d_in[4];
  const float* Wh_w  = (const float*)d_in[5];
  const float* Wh_b  = (const float*)d_in[6];
  const float* gamma = (const float*)d_in[7];
  float* out = (float*)d_out;

  const size_t nF = (size_t)kB * kN * kCK;   // 2,097,152
  const size_t nH = (size_t)kB * kC * kN;    // 16,777,216
  const size_t nR = (size_t)kB * kN;         // 32,768
  const size_t nW = 640 * 512;               // 327,680

  u16* F  = (u16*)d_ws;
  u16* G  = F + nF;
  u16* HT = G + nF;
  u16* Wcat = HT + nH;
  float* rowmax = (float*)(Wcat + nW);
  float* rsinv  = rowmax + nR;
  const size_t need = (2 * nF + nH + nW) * sizeof(u16) + 2 * nR * sizeof(float);
  if (ws_size < need) return;

  wcast_kernel<<<dim3(nW / 1024), dim3(256), 0, stream>>>(Wf_w, Wg_w, Wh_w, Wcat);
  fused_proj_kernel<<<dim3(kN / 64, kB), dim3(256), 0, stream>>>(x, Wcat, Wf_b, Wg_b, Wh_b, F, G, HT);
  stats_kernel<<<dim3(512), dim3(256), 0, stream>>>(F, G, rowmax, rsinv);
  pv_kernel<<<dim3(256), dim3(512), 0, stream>>>(x, F, G, HT, rowmax, rsinv, gamma, out);
}